// Round 3
// baseline (206.246 us; speedup 1.0000x reference)
//
#include <hip/hip_runtime.h>

// YOLO loss: preds/targets (N,7,7,30) fp32 -> scalar. 192.7 MB read.
// R2: persistent grid-stride waves, wave-private LDS slices, NO barriers in
// the hot loop. R0/R1 showed 75 us invariant to staging mechanism and to
// HBM-vs-L3 data source -> block-generation serialization (stage, full
// drain, die) was the bottleneck, not bandwidth.

#define SGRID 7
#define DDIM 30
#define NCLS 20
#define LAMBDA_NOOBJ 0.5f
#define IOU_EPS 1e-10f

#define THREADS 128                       // 2 waves/block
#define WPB (THREADS / 64)                // waves per block
#define SLICE_CELLS 64                    // cells per wave-iteration
#define SLICE_FLOATS (SLICE_CELLS * DDIM) // 1920 floats = 480 float4
#define GRID_BLOCKS 1280                  // 5 blocks/CU * 256 CU (30.7KB LDS -> 5/CU)

__device__ __forceinline__ float cell_loss(const float* pv, const float* tv) {
    float loss = 0.0f;
    // IoU per box (center format).
    float iou0 = 0.0f, iou1 = 0.0f;
#pragma unroll
    for (int b = 0; b < 2; ++b) {
        const float x1 = pv[b * 5 + 0], y1 = pv[b * 5 + 1];
        const float w1 = pv[b * 5 + 2], h1 = pv[b * 5 + 3];
        const float x2 = tv[b * 5 + 0], y2 = tv[b * 5 + 1];
        const float w2 = tv[b * 5 + 2], h2 = tv[b * 5 + 3];
        float iw = fminf(x1 + 0.5f * w1, x2 + 0.5f * w2) -
                   fmaxf(x1 - 0.5f * w1, x2 - 0.5f * w2);
        iw = fmaxf(iw, 0.0f);
        float ih = fminf(y1 + 0.5f * h1, y2 + 0.5f * h2) -
                   fmaxf(y1 - 0.5f * h1, y2 - 0.5f * h2);
        ih = fmaxf(ih, 0.0f);
        const float inter = iw * ih;
        const float uni = w1 * h1 + w2 * h2 - inter;
        const float iou = inter / (uni + IOU_EPS);
        if (b == 0) iou0 = iou; else iou1 = iou;
    }
    const bool sel1 = iou1 > iou0;  // argmax ties -> box 0

    // coord loss (selected box x,y), gated by has_obj = targets[...,4] > 0.
    {
        const float px = sel1 ? pv[5] : pv[0];
        const float py = sel1 ? pv[6] : pv[1];
        const float tx = sel1 ? tv[5] : tv[0];
        const float ty = sel1 ? tv[6] : tv[1];
        const float dx = px - tx, dy = py - ty;
        if (tv[4] > 0.0f) loss += dx * dx + dy * dy;
    }

    // class SSE + running argmax of target class (ties -> first), tracking
    // the pred at the gt class by value (no dynamic indexing).
    float gt_val = tv[10];
    float pc_gt = pv[10];
#pragma unroll
    for (int j = 0; j < NCLS; ++j) {
        const float pc = pv[10 + j], tc = tv[10 + j];
        const float d = pc - tc;
        loss += d * d;
        const bool gm = tc > gt_val;
        gt_val = gm ? tc : gt_val;
        pc_gt = gm ? pc : pc_gt;
    }

    // conf loss: w_b * iou_b^2 * (pc_gt - 1)^2
    const float c = pc_gt - 1.0f;
    const float d0 = iou0 * c, d1 = iou1 * c;
    const float w0 = sel1 ? LAMBDA_NOOBJ : 1.0f;
    const float w1 = sel1 ? 1.0f : LAMBDA_NOOBJ;
    loss += w0 * d0 * d0 + w1 * d1 * d1;
    return loss;
}

__global__ __launch_bounds__(THREADS, 3) void yolo_loss_main(
    const float* __restrict__ preds, const float* __restrict__ targets,
    float* __restrict__ partials, int n_cells) {
    __shared__ float sp[WPB * SLICE_FLOATS];
    __shared__ float st[WPB * SLICE_FLOATS];
    __shared__ float red[WPB];

    const int tid = threadIdx.x;
    const int lane = tid & 63;
    const int wlocal = tid >> 6;
    const int wglobal = (blockIdx.x * THREADS + tid) >> 6;
    const int nwaves = (GRID_BLOCKS * THREADS) >> 6;  // 2560
    const int n_slices = n_cells >> 6;                // 12544 (exact here)

    float* lp = sp + wlocal * SLICE_FLOATS;
    float* lt = st + wlocal * SLICE_FLOATS;

    float loss = 0.0f;
    for (int s = wglobal; s < n_slices; s += nwaves) {
        const float* gp = preds + (size_t)s * SLICE_FLOATS;   // 16B aligned
        const float* gt = targets + (size_t)s * SLICE_FLOATS;

        // ---- Stage 64 cells (1920 floats/tensor) into this wave's private
        // LDS slice. All 16 global loads issued before any ds_write ->
        // ~15.4 KB in flight per wave; 10 waves/CU keep the pipe full.
        float4 rp[7], rt[7];
        float2 rp2, rt2;
#pragma unroll
        for (int k = 0; k < 7; ++k) rp[k] = ((const float4*)gp)[lane + (k << 6)];
        rp2 = ((const float2*)gp)[896 + lane];
#pragma unroll
        for (int k = 0; k < 7; ++k) rt[k] = ((const float4*)gt)[lane + (k << 6)];
        rt2 = ((const float2*)gt)[896 + lane];

#pragma unroll
        for (int k = 0; k < 7; ++k) ((float4*)lp)[lane + (k << 6)] = rp[k];
        ((float2*)lp)[896 + lane] = rp2;
#pragma unroll
        for (int k = 0; k < 7; ++k) ((float4*)lt)[lane + (k << 6)] = rt[k];
        ((float2*)lt)[896 + lane] = rt2;

        // Same-wave write->read dependency: compiler's lgkmcnt waits cover
        // it; wave-private slice means NO __syncthreads needed.
        float pv[DDIM], tv[DDIM];
        {
            const float2* p2 = (const float2*)lp + lane * (DDIM / 2);
            const float2* t2 = (const float2*)lt + lane * (DDIM / 2);
#pragma unroll
            for (int i = 0; i < DDIM / 2; ++i) {
                ((float2*)pv)[i] = p2[i];
                ((float2*)tv)[i] = t2[i];
            }
        }
        loss += cell_loss(pv, tv);
    }

    // ---- Tail cells (n_cells % 64): direct guarded global loads, one wave.
    // (Dead for this shape: 802816 = 64*12544.)
    const int tail0 = n_slices << 6;
    if (blockIdx.x == 0 && wlocal == 0 && tail0 + lane < n_cells) {
        float pv[DDIM], tv[DDIM];
        const float* gp = preds + (size_t)(tail0 + lane) * DDIM;
        const float* gt = targets + (size_t)(tail0 + lane) * DDIM;
#pragma unroll
        for (int i = 0; i < DDIM; ++i) { pv[i] = gp[i]; tv[i] = gt[i]; }
        loss += cell_loss(pv, tv);
    }

    // ---- Block reduction (one barrier, outside the hot loop).
#pragma unroll
    for (int off = 32; off > 0; off >>= 1) loss += __shfl_down(loss, off, 64);
    if (lane == 0) red[wlocal] = loss;
    __syncthreads();
    if (tid == 0) {
        float ssum = 0.0f;
#pragma unroll
        for (int w = 0; w < WPB; ++w) ssum += red[w];
        partials[blockIdx.x] = ssum;
    }
}

#define RTHREADS 1024
__global__ __launch_bounds__(RTHREADS) void yolo_loss_reduce(
    const float* __restrict__ partials, int n, float inv_n,
    float* __restrict__ out) {
    __shared__ float red[RTHREADS / 64];
    float v = 0.0f;
    for (int i = threadIdx.x; i < n; i += RTHREADS) v += partials[i];
#pragma unroll
    for (int off = 32; off > 0; off >>= 1) v += __shfl_down(v, off, 64);
    if ((threadIdx.x & 63) == 0) red[threadIdx.x >> 6] = v;
    __syncthreads();
    if (threadIdx.x == 0) {
        float s = 0.0f;
#pragma unroll
        for (int w = 0; w < RTHREADS / 64; ++w) s += red[w];
        out[0] = s * inv_n;
    }
}

extern "C" void kernel_launch(void* const* d_in, const int* in_sizes, int n_in,
                              void* d_out, int out_size, void* d_ws, size_t ws_size,
                              hipStream_t stream) {
    const float* preds = (const float*)d_in[0];
    const float* targets = (const float*)d_in[1];
    float* out = (float*)d_out;

    const int total = in_sizes[0];                 // N*S*S*D
    const int n_cells = total / DDIM;              // N*S*S
    const int N = total / (SGRID * SGRID * DDIM);  // 16384

    float* partials = (float*)d_ws;  // GRID_BLOCKS floats, fully written

    yolo_loss_main<<<GRID_BLOCKS, THREADS, 0, stream>>>(preds, targets,
                                                        partials, n_cells);
    yolo_loss_reduce<<<1, RTHREADS, 0, stream>>>(partials, GRID_BLOCKS,
                                                 1.0f / (float)N, out);
}